// Round 1
// baseline (130.030 us; speedup 1.0000x reference)
//
#include <hip/hip_runtime.h>
#include <hip/hip_bf16.h>
#include <math.h>

// Problem constants (fixed by reference setup_inputs)
#define BN 8192       // batch
#define DK 256        // embedding dim (= GEMM K)
#define TM 128        // row/col tile
#define NP 41         // partial planes: 9 row-slots (dgroup) + 32 col-slots (d=1..32)
#define INV_T 1.42857142857142857f  // 1/0.7, also the fixed softmax shift m

using bf16x8 = __attribute__((ext_vector_type(8))) short;  // 8 bf16 = 4 VGPRs
using f32x4  = __attribute__((ext_vector_type(4))) float;

__device__ __forceinline__ void async_copy16(void* lds, const void* g) {
  __builtin_amdgcn_global_load_lds(
      (const __attribute__((address_space(1))) unsigned int*)g,
      (__attribute__((address_space(3))) unsigned int*)lds,
      16, 0, 0);
}

// ---------------- Kernel 1: L2-normalize rows, fp32 -> bf16 ----------------
// One wave per row: float4 loads, shuffle reduce, ushort4 stores. No LDS.
// Also initializes the partial planes (plane-major [NP][BN]) so slots that
// the triangular contrast grid never writes hold neutral values.
__global__ void norm_kernel(const float* __restrict__ E, unsigned short* __restrict__ Eb,
                            float* __restrict__ posPart, float* __restrict__ negPart) {
  const int gid = blockIdx.x * 256 + threadIdx.x;   // 0..2097151? no: 2048*256=524288
  if (gid < NP * BN) {                               // 335872 < 524288
    posPart[gid] = -1e30f;
    negPart[gid] = 0.0f;
  }
  const int wv = threadIdx.x >> 6, lane = threadIdx.x & 63;
  const int row = blockIdx.x * 4 + wv;
  const float4 x = *(const float4*)&E[(size_t)row * DK + lane * 4];
  float ss = x.x * x.x + x.y * x.y + x.z * x.z + x.w * x.w;
#pragma unroll
  for (int m = 1; m < 64; m <<= 1) ss += __shfl_xor(ss, m);
  const float scale = 1.0f / fmaxf(sqrtf(ss), 1e-12f);
  ushort4 o;
  __hip_bfloat16 h0 = __float2bfloat16(x.x * scale); o.x = *(unsigned short*)&h0;
  __hip_bfloat16 h1 = __float2bfloat16(x.y * scale); o.y = *(unsigned short*)&h1;
  __hip_bfloat16 h2 = __float2bfloat16(x.z * scale); o.z = *(unsigned short*)&h2;
  __hip_bfloat16 h3 = __float2bfloat16(x.w * scale); o.w = *(unsigned short*)&h3;
  *(ushort4*)&Eb[(size_t)row * DK + lane * 4] = o;
}

// ---------------- Kernel 2: fused sims + masked max / sum-exp ----------------
// SYMMETRIC-HALVED: sims = E E^T is symmetric, so each off-diagonal 128x128
// tile (I,J) serves BOTH row-block I (row stats, as before) and row-block J
// (column stats: per-col masked max / sum-exp, quad-lane reduced + LDS-combined
// across the two wm wave halves). Tile set: (I, (I+d)&63) for d=0..31 all I,
// plus d=32 for I<32  -> 2080 tiles vs 4096 (each unordered pair once).
// Block = (I, dgroup): dg<8 handles d=4dg..4dg+3; dg==8 (I<32 only) handles
// d=32. dg==8 mapped to blockIdx.y==0 so the light blocks dispatch first.
// Partials: plane-major [NP][BN]; plane = dg (row stats) or 8+d (col stats).
// Every (row,plane) cell has exactly one writer; unwritten cells were
// initialized by norm_kernel. Inner GEMM loop is unchanged from the 117 µs
// version (A persistent 64 KB swizzled, B staged in BK=64 chunks, 16B-chunk
// XOR swizzle, 16x16x32 bf16 MFMA, 4x4 frags/wave).
__launch_bounds__(256, 2)
__global__ void contrast_kernel(const unsigned short* __restrict__ Eb,
                                const int* __restrict__ cat,
                                float* __restrict__ posPart,
                                float* __restrict__ negPart) {
  __shared__ __align__(16) unsigned short As[TM * DK];  // 64 KB, [row][k] swizzled
  __shared__ __align__(16) unsigned short Bs[TM * 64];  // 16 KB, [col][k-chunk] swizzled

  const int tid = threadIdx.x;
  const int lane = tid & 63;
  const int wv = tid >> 6;
  const int wm = wv >> 1;      // wave row (0..1)
  const int wn = wv & 1;       // wave col (0..1)
  const int quad = lane >> 4;
  const int l16 = lane & 15;
  const int sw = l16 & 7;      // per-lane swizzle key (row&7 == l16&7)

  const int I = blockIdx.x;
  const int dg = (blockIdx.y == 0) ? 8 : (int)blockIdx.y - 1;  // light blocks first
  if (dg == 8 && I >= 32) return;      // d=32 tiles exist only for I<32
  const int ntiles = (dg == 8) ? 1 : 4;
  const int rowBase = I * TM;

  // ---- stage A tile: 64 KB, swizzled source ----
  {
    const char* gbase = (const char*)(Eb + (size_t)rowBase * DK);
#pragma unroll
    for (int i = 0; i < 16; ++i) {
      const int chunk = tid + i * 256;   // LDS 16B-chunk index (lane-contiguous)
      const int row = chunk >> 5;        // 32 chunks per 512B row
      const int c = chunk & 31;
      async_copy16((char*)As + chunk * 16,
                   gbase + row * 512 + (c ^ (row & 7)) * 16);
    }
  }

  // Rows owned by this lane (C layout: col=lane&15, row=quad*4+reg):
  int rowIdx[16];
  int catRow[16];
  float posmx[16], negsm[16];
#pragma unroll
  for (int ti = 0; ti < 4; ++ti)
#pragma unroll
    for (int r = 0; r < 4; ++r) {
      const int si = ti * 4 + r;
      rowIdx[si] = rowBase + wm * 64 + ti * 16 + quad * 4 + r;
      catRow[si] = cat[rowIdx[si]];
      posmx[si] = -1e30f;
      negsm[si] = 0.0f;
    }

#pragma unroll 1
  for (int t = 0; t < ntiles; ++t) {
    const int d = (dg == 8) ? 32 : dg * 4 + t;   // block-distance of this tile
    const int J = (I + d) & 63;
    const int colBase = J * TM;

    f32x4 acc[4][4];
#pragma unroll
    for (int ti = 0; ti < 4; ++ti)
#pragma unroll
      for (int tj = 0; tj < 4; ++tj)
        acc[ti][tj] = f32x4{0.f, 0.f, 0.f, 0.f};

#pragma unroll 1
    for (int kc = 0; kc < 4; ++kc) {
      __syncthreads();  // prev Bs consumers done (first iter: covers A wait too)
      {
        const int col8 = tid >> 3;   // col within tile (+32 per it)
        const int c = tid & 7;       // 16B chunk within 128B k-slab
        const char* g = (const char*)Eb +
                        (size_t)(colBase + col8) * 512 +
                        kc * 128 + ((c ^ (col8 & 7)) * 16);
        char* l = (char*)Bs + tid * 16;
#pragma unroll
        for (int it = 0; it < 4; ++it)   // col8+32: (col8&7) unchanged
          async_copy16(l + it * 4096, g + (size_t)it * 32 * 512);
      }
      __syncthreads();  // Bs ready (barrier drains vmcnt)

#pragma unroll
      for (int s = 0; s < 2; ++s) {
        bf16x8 a[4], b[4];
#pragma unroll
        for (int ti = 0; ti < 4; ++ti)
          a[ti] = *(const bf16x8*)&As[(wm * 64 + ti * 16 + l16) * DK +
                                      (((kc * 8 + s * 4 + quad) ^ sw) << 3)];
#pragma unroll
        for (int tj = 0; tj < 4; ++tj)
          b[tj] = *(const bf16x8*)&Bs[(wn * 64 + tj * 16 + l16) * 64 +
                                      (((s * 4 + quad) ^ sw) << 3)];
#pragma unroll
        for (int ti = 0; ti < 4; ++ti)
#pragma unroll
          for (int tj = 0; tj < 4; ++tj)
            acc[ti][tj] = __builtin_amdgcn_mfma_f32_16x16x32_bf16(a[ti], b[tj], acc[ti][tj], 0, 0, 0);
      }
    }

    // ---- fused epilogue for this 128x128 tile (acc = raw cosines) ----
    int catCol[4], colIdx[4];
#pragma unroll
    for (int tj = 0; tj < 4; ++tj) {
      colIdx[tj] = colBase + wn * 64 + tj * 16 + l16;
      catCol[tj] = cat[colIdx[tj]];
    }
    // column-stat partials (this lane's 16 rows), written only when d != 0
    float cp[4], cn[4];
#pragma unroll
    for (int tj = 0; tj < 4; ++tj) { cp[tj] = -1e30f; cn[tj] = 0.0f; }

#pragma unroll
    for (int ti = 0; ti < 4; ++ti)
#pragma unroll
      for (int r = 0; r < 4; ++r) {
        const int si = ti * 4 + r;
        float pm = posmx[si];
        float ns = negsm[si];
#pragma unroll
        for (int tj = 0; tj < 4; ++tj) {
          const float v = acc[ti][tj][r];
          const bool same = (catRow[si] == catCol[tj]);
          const bool self = (rowIdx[si] == colIdx[tj]);
          const float e = __expf(__fmaf_rn(v, INV_T, -INV_T));
          const float en = same ? 0.0f : e;     // negative contribution (shared)
          ns += en;
          pm = (same && !self) ? fmaxf(pm, v) : pm;
          cn[tj] += en;                          // col negatives (same predicate)
          cp[tj] = same ? fmaxf(cp[tj], v) : cp[tj];  // col positives (self only when d==0, not written)
        }
        posmx[si] = pm;
        negsm[si] = ns;
      }

    // ---- column-stat reduce: quad lanes, then wm halves via Bs scratch ----
#pragma unroll
    for (int tj = 0; tj < 4; ++tj) {
      cp[tj] = fmaxf(cp[tj], __shfl_xor(cp[tj], 16));
      cp[tj] = fmaxf(cp[tj], __shfl_xor(cp[tj], 32));
      cn[tj] += __shfl_xor(cn[tj], 16);
      cn[tj] += __shfl_xor(cn[tj], 32);
    }
    float* sp = (float*)Bs;    // 1 KB scratch; Bs dead until next tile's staging
    __syncthreads();           // all waves done reading Bs for MFMA
    if (wm == 1 && quad == 0) {
#pragma unroll
      for (int tj = 0; tj < 4; ++tj) {
        sp[wn * 64 + tj * 16 + l16] = cp[tj];
        sp[128 + wn * 64 + tj * 16 + l16] = cn[tj];
      }
    }
    __syncthreads();           // scratch visible; next kc=0 barrier covers reads
    if (d != 0 && wm == 0 && quad == 0) {
#pragma unroll
      for (int tj = 0; tj < 4; ++tj) {
        const int C = colIdx[tj];   // coalesced over l16
        posPart[(size_t)(8 + d) * BN + C] = fmaxf(cp[tj], sp[wn * 64 + tj * 16 + l16]);
        negPart[(size_t)(8 + d) * BN + C] = cn[tj] + sp[128 + wn * 64 + tj * 16 + l16];
      }
    }
  }

  // ---- row stats: reduce across the 16 lanes sharing each row (cols split) ----
#pragma unroll
  for (int si = 0; si < 16; ++si) {
    float pm = posmx[si], ns = negsm[si];
#pragma unroll
    for (int m = 1; m < 16; m <<= 1) {
      pm = fmaxf(pm, __shfl_xor(pm, m));
      ns += __shfl_xor(ns, m);
    }
    posmx[si] = pm;
    negsm[si] = ns;
  }

  // ---- combine the wn=0 / wn=1 wave halves via LDS (reuse As) ----
  float* red = (float*)As;  // [0..127]=pos, [128..255]=neg
  __syncthreads();
  if (wn == 1 && l16 == 0) {
#pragma unroll
    for (int si = 0; si < 16; ++si) {
      const int rl = wm * 64 + (si >> 2) * 16 + quad * 4 + (si & 3);
      red[rl] = posmx[si];
      red[128 + rl] = negsm[si];
    }
  }
  __syncthreads();
  if (wn == 0 && l16 == 0) {
#pragma unroll
    for (int si = 0; si < 16; ++si) {
      const int rl = wm * 64 + (si >> 2) * 16 + quad * 4 + (si & 3);
      const float pm = fmaxf(posmx[si], red[rl]);
      const float ns = negsm[si] + red[128 + rl];
      posPart[(size_t)dg * BN + rowBase + rl] = pm;  // raw cosine max
      negPart[(size_t)dg * BN + rowBase + rl] = ns;
    }
  }
}

// ---------------- Kernel 3a: per-row loss, atomic accumulate ----------------
// Grid 32 x 256: one thread per row; plane-major partials -> each of the NP
// reads is a fully-coalesced 256-thread load.
__global__ void finalize1_kernel(const float* __restrict__ posPart,
                                 const float* __restrict__ negPart,
                                 float* __restrict__ accum) {
  const int tid = threadIdx.x;
  const int row = blockIdx.x * 256 + tid;
  float pm = -1e30f, ns = 0.0f;
#pragma unroll
  for (int g = 0; g < NP; ++g) {
    pm = fmaxf(pm, posPart[(size_t)g * BN + row]);
    ns += negPart[(size_t)g * BN + row];
  }
  float loss = 0.0f, c = 0.0f;
  if (pm > -1e29f && ns > 0.0f) {   // valid: has positive AND negative
    const float pos = pm * INV_T;
    const float lse = INV_T + logf(expf(pos - INV_T) + ns);
    loss = lse - pos;
    c = 1.0f;
  }
#pragma unroll
  for (int m = 1; m < 64; m <<= 1) {
    loss += __shfl_xor(loss, m);
    c += __shfl_xor(c, m);
  }
  __shared__ float sL[4], sC[4];
  const int wv = tid >> 6, lane = tid & 63;
  if (lane == 0) { sL[wv] = loss; sC[wv] = c; }
  __syncthreads();
  if (tid == 0) {
    atomicAdd(&accum[0], sL[0] + sL[1] + sL[2] + sL[3]);
    atomicAdd(&accum[1], sC[0] + sC[1] + sC[2] + sC[3]);
  }
}

// ---------------- Kernel 3b: final division ----------------
__global__ void finalize2_kernel(const float* __restrict__ accum,
                                 float* __restrict__ out) {
  out[0] = (accum[1] > 0.0f) ? accum[0] / accum[1] : 0.0f;
}

extern "C" void kernel_launch(void* const* d_in, const int* in_sizes, int n_in,
                              void* d_out, int out_size, void* d_ws, size_t ws_size,
                              hipStream_t stream) {
  const float* E = (const float*)d_in[0];
  const int* cat = (const int*)d_in[1];
  // d_in[2] (font_labels) unused by the reference.

  // Workspace: [0,4MB) bf16 normalized embeddings; [NP][BN] partials x2; 8B accum.
  unsigned short* Eb = (unsigned short*)d_ws;
  float* posPart = (float*)((char*)d_ws + (size_t)BN * DK * 2);
  float* negPart = posPart + (size_t)NP * BN;
  float* accum = negPart + (size_t)NP * BN;
  float* out = (float*)d_out;

  hipMemsetAsync(accum, 0, 2 * sizeof(float), stream);
  hipLaunchKernelGGL(norm_kernel, dim3(BN / 4), dim3(256), 0, stream,
                     E, Eb, posPart, negPart);
  hipLaunchKernelGGL(contrast_kernel, dim3(BN / TM, 9), dim3(256), 0, stream,
                     Eb, cat, posPart, negPart);
  hipLaunchKernelGGL(finalize1_kernel, dim3(BN / 256), dim3(256), 0, stream,
                     posPart, negPart, accum);
  hipLaunchKernelGGL(finalize2_kernel, dim3(1), dim3(1), 0, stream, accum, out);
}